// Round 1
// 823.342 us; speedup vs baseline: 1.3363x; 1.3363x over previous
//
#include <hip/hip_runtime.h>
#include <cmath>

#define NN 50000
#define EE 600000

#define LOG2E 1.44269504088896340736f
#define LN2F  0.69314718055994530942f

__device__ __forceinline__ float fast_exp2(float x) { return __builtin_amdgcn_exp2f(x); }
__device__ __forceinline__ float fast_log2(float x) { return __builtin_amdgcn_logf(x); }
__device__ __forceinline__ float fast_rcp(float x)  { return __builtin_amdgcn_rcpf(x); }

// softplus(x) = ln2 * (max(x2,0) + log2(1 + 2^-|x2|)),  x2 = x*log2e
__device__ __forceinline__ float softplus_fast(float x) {
  float x2 = x * LOG2E;
  return LN2F * (fmaxf(x2, 0.f) + fast_log2(1.f + fast_exp2(-fabsf(x2))));
}

// ---------------- zero: deg[] + stats doubles ----------------------------------
__global__ __launch_bounds__(256) void zero_kernel(int* __restrict__ deg,
                                                   float* __restrict__ stats_f) {
  int i = blockIdx.x * 256 + threadIdx.x;
  if (i < NN) deg[i] = 0;
  if (i < 512) stats_f[i] = 0.f;  // 256 doubles
}

// ---------------- GEMM: C[64 rows,128] = softplus(A@B + bias), K=128 ----------
__global__ __launch_bounds__(256) void gemm128_act(const float* __restrict__ A,
                                                   const float* __restrict__ B,
                                                   const float* __restrict__ bias,
                                                   float* __restrict__ Cmat,
                                                   int nrows) {
  __shared__ float Ash[64][68];
  __shared__ float Bsh[64][128];
  const int tid = threadIdx.x;
  const int row0 = blockIdx.x * 64;
  const int tx = tid & 15, ty = tid >> 4;
  const int r0 = ty * 4, c0 = tx * 4;

  float acc[4][8];
#pragma unroll
  for (int r = 0; r < 4; ++r)
#pragma unroll
    for (int j = 0; j < 8; ++j) acc[r][j] = 0.f;

  for (int kb = 0; kb < 2; ++kb) {
    for (int i = tid; i < 64 * 16; i += 256) {
      int r = i >> 4, k4 = i & 15;
      int gr = row0 + r; if (gr >= nrows) gr = nrows - 1;
      float4 v = ((const float4*)(A + (size_t)gr * 128 + kb * 64))[k4];
      *(float4*)&Ash[r][k4 * 4] = v;
    }
    for (int i = tid; i < 64 * 32; i += 256) {
      int k = i >> 5, c4 = i & 31;
      float4 v = ((const float4*)(B + (size_t)(kb * 64 + k) * 128))[c4];
      *(float4*)&Bsh[k][c4 * 4] = v;
    }
    __syncthreads();
#pragma unroll 4
    for (int k = 0; k < 64; ++k) {
      float aa[4] = {Ash[r0 + 0][k], Ash[r0 + 1][k], Ash[r0 + 2][k], Ash[r0 + 3][k]};
      float4 b0 = *(const float4*)&Bsh[k][c0];
      float4 b1 = *(const float4*)&Bsh[k][c0 + 64];
      float bb[8] = {b0.x, b0.y, b0.z, b0.w, b1.x, b1.y, b1.z, b1.w};
#pragma unroll
      for (int r = 0; r < 4; ++r)
#pragma unroll
        for (int j = 0; j < 8; ++j) acc[r][j] = fmaf(aa[r], bb[j], acc[r][j]);
    }
    __syncthreads();
  }

  float bv[8];
#pragma unroll
  for (int j = 0; j < 8; ++j) bv[j] = bias[j < 4 ? c0 + j : c0 + 60 + j];
#pragma unroll
  for (int r = 0; r < 4; ++r) {
    int gr = row0 + r0 + r;
    if (gr < nrows) {
      float tmp[8];
#pragma unroll
      for (int j = 0; j < 8; ++j) tmp[j] = softplus_fast(acc[r][j] + bv[j]);
      *(float4*)(Cmat + (size_t)gr * 128 + c0) = make_float4(tmp[0], tmp[1], tmp[2], tmp[3]);
      *(float4*)(Cmat + (size_t)gr * 128 + c0 + 64) = make_float4(tmp[4], tmp[5], tmp[6], tmp[7]);
    }
  }
}

// ------------- fused 4-way GEMM for P slabs: out scaled by LOG2E --------------
// blockIdx.y selects: 0: Pif=(A@Wf[:C]+bf)*L  1: Pjf=(A@Wf[C:2C])*L
//                     2: Pis=(A@Ws[:C]+bs)*L  3: Pjs=(A@Ws[C:2C])*L
__global__ __launch_bounds__(256) void gemm128_p4(const float* __restrict__ A,
                                                  const float* __restrict__ Wf,
                                                  const float* __restrict__ Ws,
                                                  const float* __restrict__ bf,
                                                  const float* __restrict__ bs,
                                                  float* __restrict__ Pif,
                                                  float* __restrict__ Pjf,
                                                  float* __restrict__ Pis,
                                                  float* __restrict__ Pjs,
                                                  int nrows) {
  __shared__ float Ash[64][68];
  __shared__ float Bsh[64][128];
  const int tid = threadIdx.x;
  const int row0 = blockIdx.x * 64;
  const int which = blockIdx.y;

  const float* B;  const float* bias;  float* Cmat;
  if (which == 0)      { B = Wf;             bias = bf;      Cmat = Pif; }
  else if (which == 1) { B = Wf + 128 * 128; bias = nullptr; Cmat = Pjf; }
  else if (which == 2) { B = Ws;             bias = bs;      Cmat = Pis; }
  else                 { B = Ws + 128 * 128; bias = nullptr; Cmat = Pjs; }

  const int tx = tid & 15, ty = tid >> 4;
  const int r0 = ty * 4, c0 = tx * 4;

  float acc[4][8];
#pragma unroll
  for (int r = 0; r < 4; ++r)
#pragma unroll
    for (int j = 0; j < 8; ++j) acc[r][j] = 0.f;

  for (int kb = 0; kb < 2; ++kb) {
    for (int i = tid; i < 64 * 16; i += 256) {
      int r = i >> 4, k4 = i & 15;
      int gr = row0 + r; if (gr >= nrows) gr = nrows - 1;
      float4 v = ((const float4*)(A + (size_t)gr * 128 + kb * 64))[k4];
      *(float4*)&Ash[r][k4 * 4] = v;
    }
    for (int i = tid; i < 64 * 32; i += 256) {
      int k = i >> 5, c4 = i & 31;
      float4 v = ((const float4*)(B + (size_t)(kb * 64 + k) * 128))[c4];
      *(float4*)&Bsh[k][c4 * 4] = v;
    }
    __syncthreads();
#pragma unroll 4
    for (int k = 0; k < 64; ++k) {
      float aa[4] = {Ash[r0 + 0][k], Ash[r0 + 1][k], Ash[r0 + 2][k], Ash[r0 + 3][k]};
      float4 b0 = *(const float4*)&Bsh[k][c0];
      float4 b1 = *(const float4*)&Bsh[k][c0 + 64];
      float bb[8] = {b0.x, b0.y, b0.z, b0.w, b1.x, b1.y, b1.z, b1.w};
#pragma unroll
      for (int r = 0; r < 4; ++r)
#pragma unroll
        for (int j = 0; j < 8; ++j) acc[r][j] = fmaf(aa[r], bb[j], acc[r][j]);
    }
    __syncthreads();
  }

  float bv[8];
#pragma unroll
  for (int j = 0; j < 8; ++j)
    bv[j] = bias ? bias[j < 4 ? c0 + j : c0 + 60 + j] : 0.f;
#pragma unroll
  for (int r = 0; r < 4; ++r) {
    int gr = row0 + r0 + r;
    if (gr < nrows) {
      float tmp[8];
#pragma unroll
      for (int j = 0; j < 8; ++j) tmp[j] = (acc[r][j] + bv[j]) * LOG2E;
      *(float4*)(Cmat + (size_t)gr * 128 + c0) = make_float4(tmp[0], tmp[1], tmp[2], tmp[3]);
      *(float4*)(Cmat + (size_t)gr * 128 + c0 + 64) = make_float4(tmp[4], tmp[5], tmp[6], tmp[7]);
    }
  }
}

// ---------------- e = softplus(edge_attr @ Wsh + bsh), 16 lanes per edge -------
__global__ __launch_bounds__(256) void edge_e_kernel(const float* __restrict__ edge_attr,
                                                     const float* __restrict__ Wsh,
                                                     const float* __restrict__ bsh,
                                                     float* __restrict__ ebuf) {
  __shared__ float wsh[128];
  int tid = threadIdx.x;
  if (tid < 128) wsh[tid] = Wsh[tid];
  __syncthreads();
  int wave = tid >> 6, lane = tid & 63;
  int sub = lane >> 4, l16 = lane & 15;
  int edge = (blockIdx.x * 4 + wave) * 4 + sub;
  const float4* row = (const float4*)(edge_attr + (size_t)edge * 128);
  float4 v0 = row[l16], v1 = row[l16 + 16];
  float4 w0 = *(const float4*)&wsh[l16 * 4];
  float4 w1 = *(const float4*)&wsh[64 + l16 * 4];
  float p = v0.x * w0.x + v0.y * w0.y + v0.z * w0.z + v0.w * w0.w +
            v1.x * w1.x + v1.y * w1.y + v1.z * w1.z + v1.w * w1.w;
  p += __shfl_xor(p, 1);
  p += __shfl_xor(p, 2);
  p += __shfl_xor(p, 4);
  p += __shfl_xor(p, 8);
  if (l16 == 0) ebuf[edge] = softplus_fast(p + bsh[0]);
}

// ---------------- CSR build: histogram ----------------------------------------
__global__ __launch_bounds__(256) void hist_kernel(const int* __restrict__ eidx,
                                                   int* __restrict__ deg) {
  int e = blockIdx.x * 256 + threadIdx.x;
  if (e < EE) atomicAdd(&deg[eidx[EE + e]], 1);
}

// ---------------- CSR build: single-block exclusive scan (int4, 4/thread) ------
__global__ __launch_bounds__(1024) void scan_kernel(const int* __restrict__ deg,
                                                    int* __restrict__ rowptr,
                                                    int* __restrict__ cur) {
  __shared__ int wscan[16];
  __shared__ int chunk_total_sh;
  int tid = threadIdx.x;
  int wid = tid >> 6, lane = tid & 63;
  int running = 0;
  for (int base = 0; base < NN; base += 4096) {
    int i0 = base + tid * 4;
    int4 v = make_int4(0, 0, 0, 0);
    if (i0 + 3 < NN) {
      v = *(const int4*)(deg + i0);
    } else {
      if (i0 < NN)     v.x = deg[i0];
      if (i0 + 1 < NN) v.y = deg[i0 + 1];
      if (i0 + 2 < NN) v.z = deg[i0 + 2];
      if (i0 + 3 < NN) v.w = deg[i0 + 3];
    }
    int t0 = v.x, t1 = t0 + v.y, t2 = t1 + v.z, t3 = t2 + v.w;  // incl within thread
    int s = t3;  // inclusive scan of thread sums within wave
#pragma unroll
    for (int off = 1; off < 64; off <<= 1) {
      int t = __shfl_up(s, off);
      if (lane >= off) s += t;
    }
    if (lane == 63) wscan[wid] = s;
    __syncthreads();
    if (wid == 0 && lane < 16) {
      int w = wscan[lane];
#pragma unroll
      for (int off = 1; off < 16; off <<= 1) {
        int t = __shfl_up(w, off);
        if (lane >= off) w += t;
      }
      wscan[lane] = w;
      if (lane == 15) chunk_total_sh = w;
    }
    __syncthreads();
    int wexcl = (wid == 0) ? 0 : wscan[wid - 1];
    int texcl = running + wexcl + (s - t3);  // exclusive prefix of this thread's 1st elem
    int4 r = make_int4(texcl, texcl + t0, texcl + t1, texcl + t2);
    if (i0 + 3 < NN) {
      *(int4*)(rowptr + i0) = r;
      *(int4*)(cur + i0) = r;
    } else {
      if (i0 < NN)     { rowptr[i0] = r.x;     cur[i0] = r.x; }
      if (i0 + 1 < NN) { rowptr[i0 + 1] = r.y; cur[i0 + 1] = r.y; }
      if (i0 + 2 < NN) { rowptr[i0 + 2] = r.z; cur[i0 + 2] = r.z; }
      if (i0 + 3 < NN) { rowptr[i0 + 3] = r.w; cur[i0 + 3] = r.w; }
    }
    running += chunk_total_sh;
    __syncthreads();  // protect wscan/chunk_total_sh for next chunk
  }
  if (tid == 0) rowptr[NN] = EE;
}

// ---------------- CSR build: scatter (src, e-value) into dst-sorted order ------
__global__ __launch_bounds__(256) void scatter_kernel(const int* __restrict__ eidx,
                                                      const float* __restrict__ ebuf,
                                                      int* __restrict__ cur,
                                                      int* __restrict__ srcs,
                                                      float* __restrict__ evals) {
  int e = blockIdx.x * 256 + threadIdx.x;
  if (e < EE) {
    int dst = eidx[EE + e];
    int pos = atomicAdd(&cur[dst], 1);
    srcs[pos] = eidx[e];
    evals[pos] = ebuf[e];
  }
}

// ---------------- gather-side aggregation: 32 lanes per node, no atomics -------
// All P slabs (and wfe/wse) are pre-scaled by LOG2E, so sigmoid/softplus use raw
// v_exp/v_log/v_rcp with no per-edge scaling muls; the global ln2 factor on the
// softplus is applied once per node after the loop. Row gathers for iteration
// k+1 are issued before iteration k's math (1-deep software pipeline).
__global__ __launch_bounds__(256) void aggregate_kernel(const int* __restrict__ rowptr,
                                                        const int* __restrict__ srcs,
                                                        const float* __restrict__ evals,
                                                        float* __restrict__ pifagg,
                                                        const float* __restrict__ Pjf,
                                                        const float* __restrict__ Pis,
                                                        const float* __restrict__ Pjs,
                                                        const float* __restrict__ Wf_e,
                                                        const float* __restrict__ Ws_e) {
  __shared__ float wfe[128], wse[128];
  int tid = threadIdx.x;
  if (tid < 128) wfe[tid] = Wf_e[tid] * LOG2E;
  else wse[tid - 128] = Ws_e[tid - 128] * LOG2E;
  __syncthreads();
  int slot = tid >> 5, lane = tid & 31;
  int node = blockIdx.x * 8 + slot;   // grid sized exactly: 6250*8 == 50000
  float4 fi = ((const float4*)(pifagg + (size_t)node * 128))[lane];
  float4 si = ((const float4*)(Pis + (size_t)node * 128))[lane];
  float4 wf4 = *(const float4*)&wfe[lane * 4];
  float4 ws4 = *(const float4*)&wse[lane * 4];
  float4 acc = make_float4(0.f, 0.f, 0.f, 0.f);

  int beg = rowptr[node], end = rowptr[node + 1];
  if (beg < end) {
    int src = srcs[beg];
    float eV = evals[beg];
    float4 fj = ((const float4*)(Pjf + (size_t)src * 128))[lane];
    float4 sj = ((const float4*)(Pjs + (size_t)src * 128))[lane];
    int sN = 0; float eN = 0.f;
    if (beg + 1 < end) { sN = srcs[beg + 1]; eN = evals[beg + 1]; }
    for (int k = beg; ; ) {
      bool more = (k + 1 < end);
      float4 fjn, sjn;
      if (more) {  // prefetch next rows (consumed only next iteration)
        fjn = ((const float4*)(Pjf + (size_t)sN * 128))[lane];
        sjn = ((const float4*)(Pjs + (size_t)sN * 128))[lane];
      }
      int sNN = 0; float eNN = 0.f;
      if (k + 2 < end) { sNN = srcs[k + 2]; eNN = evals[k + 2]; }
      {
        float a2, b2, g, sp;
        a2 = fmaf(eV, wf4.x, fi.x) + fj.x;
        g  = fast_rcp(1.f + fast_exp2(-a2));
        b2 = fmaf(eV, ws4.x, si.x) + sj.x;
        sp = fmaxf(b2, 0.f) + fast_log2(1.f + fast_exp2(-fabsf(b2)));
        acc.x = fmaf(g, sp, acc.x);
        a2 = fmaf(eV, wf4.y, fi.y) + fj.y;
        g  = fast_rcp(1.f + fast_exp2(-a2));
        b2 = fmaf(eV, ws4.y, si.y) + sj.y;
        sp = fmaxf(b2, 0.f) + fast_log2(1.f + fast_exp2(-fabsf(b2)));
        acc.y = fmaf(g, sp, acc.y);
        a2 = fmaf(eV, wf4.z, fi.z) + fj.z;
        g  = fast_rcp(1.f + fast_exp2(-a2));
        b2 = fmaf(eV, ws4.z, si.z) + sj.z;
        sp = fmaxf(b2, 0.f) + fast_log2(1.f + fast_exp2(-fabsf(b2)));
        acc.z = fmaf(g, sp, acc.z);
        a2 = fmaf(eV, wf4.w, fi.w) + fj.w;
        g  = fast_rcp(1.f + fast_exp2(-a2));
        b2 = fmaf(eV, ws4.w, si.w) + sj.w;
        sp = fmaxf(b2, 0.f) + fast_log2(1.f + fast_exp2(-fabsf(b2)));
        acc.w = fmaf(g, sp, acc.w);
      }
      if (!more) break;
      fj = fjn; sj = sjn; eV = eN; sN = sNN; eN = eNN; ++k;
    }
  }
  acc.x *= LN2F; acc.y *= LN2F; acc.z *= LN2F; acc.w *= LN2F;
  ((float4*)(pifagg + (size_t)node * 128))[lane] = acc;
}

// ---------------- per-channel sum / sumsq over aggr ----------------------------
__global__ __launch_bounds__(256) void stats_kernel(const float* __restrict__ aggr,
                                                    double* __restrict__ dstats) {
  int tid = threadIdx.x;
  int c = tid & 127, half = tid >> 7;
  int rbase = blockIdx.x * 512;
  float s = 0.f, q = 0.f;
  for (int i = 0; i < 256; ++i) {
    int r = rbase + half + i * 2;
    if (r < NN) {
      float v = aggr[(size_t)r * 128 + c];
      s += v;
      q += v * v;
    }
  }
  __shared__ float shs[256], shq[256];
  shs[tid] = s;
  shq[tid] = q;
  __syncthreads();
  if (tid < 128) {
    double ts = (double)shs[tid] + (double)shs[tid + 128];
    double tq = (double)shq[tid] + (double)shq[tid + 128];
    atomicAdd(&dstats[c], ts);
    atomicAdd(&dstats[128 + c], tq);
  }
}

// ---------------- fold BN into per-channel scale/shift -------------------------
__global__ void bn_params_kernel(const double* __restrict__ dstats,
                                 const float* __restrict__ gamma,
                                 const float* __restrict__ beta,
                                 float* __restrict__ scsh) {
  int c = threadIdx.x;
  double mean = dstats[c] / (double)NN;
  double var = dstats[128 + c] / (double)NN - mean * mean;
  double rs = 1.0 / sqrt(var + 1e-5);
  double sc = (double)gamma[c] * rs;
  scsh[c] = (float)sc;
  scsh[128 + c] = (float)((double)beta[c] - mean * sc);
}

// ---------------- y = 2*out + aggr*scale + shift (in-place on d_out) -----------
__global__ __launch_bounds__(256) void finalize_kernel(const float* __restrict__ outbuf,
                                                       const float* __restrict__ scsh,
                                                       float* __restrict__ dout) {
  __shared__ float sc[128], sh[128];
  int tid = threadIdx.x;
  if (tid < 128) sc[tid] = scsh[tid];
  else sh[tid - 128] = scsh[tid];
  __syncthreads();
  size_t i = (size_t)blockIdx.x * 256 + tid;
  size_t stride = (size_t)gridDim.x * 256;
  const float4* o4 = (const float4*)outbuf;
  float4* d4 = (float4*)dout;
  const size_t n4 = (size_t)NN * 32;
  for (; i < n4; i += stride) {
    int c4 = (int)(i & 31) * 4;
    float4 a = d4[i], o = o4[i];
    float4 r;
    r.x = 2.f * o.x + a.x * sc[c4 + 0] + sh[c4 + 0];
    r.y = 2.f * o.y + a.y * sc[c4 + 1] + sh[c4 + 1];
    r.z = 2.f * o.z + a.z * sc[c4 + 2] + sh[c4 + 2];
    r.w = 2.f * o.w + a.w * sc[c4 + 3] + sh[c4 + 3];
    d4[i] = r;
  }
}

extern "C" void kernel_launch(void* const* d_in, const int* in_sizes, int n_in,
                              void* d_out, int out_size, void* d_ws, size_t ws_size,
                              hipStream_t stream) {
  const float* h         = (const float*)d_in[0];
  const int*   eidx      = (const int*)d_in[1];
  const float* edge_attr = (const float*)d_in[3];
  const float* W0    = (const float*)d_in[4];
  const float* b0    = (const float*)d_in[5];
  const float* Wsh   = (const float*)d_in[6];
  const float* bsh   = (const float*)d_in[7];
  const float* Wf    = (const float*)d_in[8];
  const float* bf    = (const float*)d_in[9];
  const float* Ws    = (const float*)d_in[10];
  const float* bs    = (const float*)d_in[11];
  const float* gamma = (const float*)d_in[12];
  const float* beta  = (const float*)d_in[13];
  float* dout = (float*)d_out;

  // Workspace layout (~110.2 MB). dstats (doubles) 16-aligned; rowptr padded to
  // NN+4 ints so cur stays 16B-aligned for int4 stores in scan_kernel.
  char* ws = (char*)d_ws;
  const size_t NCb = (size_t)NN * 128 * 4;  // 25.6 MB
  float*  outbuf = (float*)ws;                         // [NN,128]
  float*  Pjf    = (float*)(ws + NCb);                 // [NN,128] (xLOG2E)
  float*  Pis    = (float*)(ws + NCb * 2);             // [NN,128] (xLOG2E)
  float*  Pjs    = (float*)(ws + NCb * 3);             // [NN,128] (xLOG2E)
  char*   p0     = ws + NCb * 4;                       // 102,400,000 (16-aligned)
  float*  ebuf   = (float*)p0;                  p0 += (size_t)EE * 4;
  int*    srcs   = (int*)p0;                    p0 += (size_t)EE * 4;
  float*  evals  = (float*)p0;                  p0 += (size_t)EE * 4;
  double* dstats = (double*)p0;                 p0 += 256 * 8;               // 16-aligned
  float*  scsh   = (float*)p0;                  p0 += 256 * 4;
  int*    deg    = (int*)p0;                    p0 += (size_t)NN * 4;        // 16-aligned
  int*    rowptr = (int*)p0;                    p0 += (size_t)(NN + 4) * 4;  // padded
  int*    cur    = (int*)p0;                    // 16-aligned
  float*  Pif    = dout;  // pi_f slab (xLOG2E) lives in d_out; aggregate overwrites

  // 1. zero deg + stats
  zero_kernel<<<(NN + 255) / 256, 256, 0, stream>>>(deg, (float*)dstats);

  // 2. out = softplus(h @ W0 + b0)
  const int gblocks = (NN + 63) / 64;
  gemm128_act<<<gblocks, 256, 0, stream>>>(h, W0, b0, outbuf, NN);

  // 3. all four P slabs in one dispatch (pre-scaled by LOG2E)
  gemm128_p4<<<dim3(gblocks, 4), 256, 0, stream>>>(outbuf, Wf, Ws, bf, bs,
                                                   Pif, Pjf, Pis, Pjs, NN);

  // 4. e = softplus(edge_attr @ Wsh + bsh)
  edge_e_kernel<<<EE / 16, 256, 0, stream>>>(edge_attr, Wsh, bsh, ebuf);

  // 5. CSR build by dst
  hist_kernel<<<(EE + 255) / 256, 256, 0, stream>>>(eidx, deg);
  scan_kernel<<<1, 1024, 0, stream>>>(deg, rowptr, cur);
  scatter_kernel<<<(EE + 255) / 256, 256, 0, stream>>>(eidx, ebuf, cur, srcs, evals);

  // 6. gather-side aggregation (no atomics; writes aggr into d_out)
  aggregate_kernel<<<NN / 8, 256, 0, stream>>>(rowptr, srcs, evals, Pif, Pjf, Pis, Pjs,
                                               Wf + 256 * 128, Ws + 256 * 128);

  // 7-9. batch stats, BN fold, finalize
  stats_kernel<<<(NN + 511) / 512, 256, 0, stream>>>(dout, dstats);
  bn_params_kernel<<<1, 128, 0, stream>>>(dstats, gamma, beta, scsh);
  finalize_kernel<<<2048, 256, 0, stream>>>(outbuf, scsh, dout);
}

// Round 2
// 770.643 us; speedup vs baseline: 1.4276x; 1.0684x over previous
//
#include <hip/hip_runtime.h>
#include <hip/hip_fp16.h>
#include <cmath>

#define NN 50000
#define EE 600000

#define LOG2E 1.44269504088896340736f
#define LN2F  0.69314718055994530942f

__device__ __forceinline__ float fast_exp2(float x) { return __builtin_amdgcn_exp2f(x); }
__device__ __forceinline__ float fast_log2(float x) { return __builtin_amdgcn_logf(x); }
__device__ __forceinline__ float fast_rcp(float x)  { return __builtin_amdgcn_rcpf(x); }

// softplus(x) = ln2 * (max(x2,0) + log2(1 + 2^-|x2|)),  x2 = x*log2e
__device__ __forceinline__ float softplus_fast(float x) {
  float x2 = x * LOG2E;
  return LN2F * (fmaxf(x2, 0.f) + fast_log2(1.f + fast_exp2(-fabsf(x2))));
}

// ---------------- zero: deg[] + stats doubles ----------------------------------
__global__ __launch_bounds__(256) void zero_kernel(int* __restrict__ deg,
                                                   float* __restrict__ stats_f) {
  int i = blockIdx.x * 256 + threadIdx.x;
  if (i < NN) deg[i] = 0;
  if (i < 512) stats_f[i] = 0.f;  // 256 doubles
}

// ---------------- GEMM: C[64 rows,128] = softplus(A@B + bias), K=128 ----------
__global__ __launch_bounds__(256) void gemm128_act(const float* __restrict__ A,
                                                   const float* __restrict__ B,
                                                   const float* __restrict__ bias,
                                                   float* __restrict__ Cmat,
                                                   int nrows) {
  __shared__ float Ash[64][68];
  __shared__ float Bsh[64][128];
  const int tid = threadIdx.x;
  const int row0 = blockIdx.x * 64;
  const int tx = tid & 15, ty = tid >> 4;
  const int r0 = ty * 4, c0 = tx * 4;

  float acc[4][8];
#pragma unroll
  for (int r = 0; r < 4; ++r)
#pragma unroll
    for (int j = 0; j < 8; ++j) acc[r][j] = 0.f;

  for (int kb = 0; kb < 2; ++kb) {
    for (int i = tid; i < 64 * 16; i += 256) {
      int r = i >> 4, k4 = i & 15;
      int gr = row0 + r; if (gr >= nrows) gr = nrows - 1;
      float4 v = ((const float4*)(A + (size_t)gr * 128 + kb * 64))[k4];
      *(float4*)&Ash[r][k4 * 4] = v;
    }
    for (int i = tid; i < 64 * 32; i += 256) {
      int k = i >> 5, c4 = i & 31;
      float4 v = ((const float4*)(B + (size_t)(kb * 64 + k) * 128))[c4];
      *(float4*)&Bsh[k][c4 * 4] = v;
    }
    __syncthreads();
#pragma unroll 4
    for (int k = 0; k < 64; ++k) {
      float aa[4] = {Ash[r0 + 0][k], Ash[r0 + 1][k], Ash[r0 + 2][k], Ash[r0 + 3][k]};
      float4 b0 = *(const float4*)&Bsh[k][c0];
      float4 b1 = *(const float4*)&Bsh[k][c0 + 64];
      float bb[8] = {b0.x, b0.y, b0.z, b0.w, b1.x, b1.y, b1.z, b1.w};
#pragma unroll
      for (int r = 0; r < 4; ++r)
#pragma unroll
        for (int j = 0; j < 8; ++j) acc[r][j] = fmaf(aa[r], bb[j], acc[r][j]);
    }
    __syncthreads();
  }

  float bv[8];
#pragma unroll
  for (int j = 0; j < 8; ++j) bv[j] = bias[j < 4 ? c0 + j : c0 + 60 + j];
#pragma unroll
  for (int r = 0; r < 4; ++r) {
    int gr = row0 + r0 + r;
    if (gr < nrows) {
      float tmp[8];
#pragma unroll
      for (int j = 0; j < 8; ++j) tmp[j] = softplus_fast(acc[r][j] + bv[j]);
      *(float4*)(Cmat + (size_t)gr * 128 + c0) = make_float4(tmp[0], tmp[1], tmp[2], tmp[3]);
      *(float4*)(Cmat + (size_t)gr * 128 + c0 + 64) = make_float4(tmp[4], tmp[5], tmp[6], tmp[7]);
    }
  }
}

// ------------- fused 4-way GEMM for P slabs → fp16 interleaved slabs ----------
// Slab layout per node: 32 channel-groups x 8 halfs [f0 f1 f2 f3 s0 s1 s2 s3].
// POwn holds (pi_f+bf)*L and (pi_s+bs)*L ; PGat holds pj_f*L and pj_s*L.
// blockIdx.y: 0 -> POwn f-part, 1 -> PGat f-part, 2 -> POwn s-part, 3 -> PGat s-part
__global__ __launch_bounds__(256) void gemm128_p4(const float* __restrict__ A,
                                                  const float* __restrict__ Wf,
                                                  const float* __restrict__ Ws,
                                                  const float* __restrict__ bf,
                                                  const float* __restrict__ bs,
                                                  ushort* __restrict__ POwn,
                                                  ushort* __restrict__ PGat,
                                                  int nrows) {
  __shared__ float Ash[64][68];
  __shared__ float Bsh[64][128];
  const int tid = threadIdx.x;
  const int row0 = blockIdx.x * 64;
  const int which = blockIdx.y;

  const float* B;  const float* bias;  ushort* dstbase;  int soff;
  if (which == 0)      { B = Wf;             bias = bf;      dstbase = POwn; soff = 0; }
  else if (which == 1) { B = Wf + 128 * 128; bias = nullptr; dstbase = PGat; soff = 0; }
  else if (which == 2) { B = Ws;             bias = bs;      dstbase = POwn; soff = 4; }
  else                 { B = Ws + 128 * 128; bias = nullptr; dstbase = PGat; soff = 4; }

  const int tx = tid & 15, ty = tid >> 4;
  const int r0 = ty * 4, c0 = tx * 4;

  float acc[4][8];
#pragma unroll
  for (int r = 0; r < 4; ++r)
#pragma unroll
    for (int j = 0; j < 8; ++j) acc[r][j] = 0.f;

  for (int kb = 0; kb < 2; ++kb) {
    for (int i = tid; i < 64 * 16; i += 256) {
      int r = i >> 4, k4 = i & 15;
      int gr = row0 + r; if (gr >= nrows) gr = nrows - 1;
      float4 v = ((const float4*)(A + (size_t)gr * 128 + kb * 64))[k4];
      *(float4*)&Ash[r][k4 * 4] = v;
    }
    for (int i = tid; i < 64 * 32; i += 256) {
      int k = i >> 5, c4 = i & 31;
      float4 v = ((const float4*)(B + (size_t)(kb * 64 + k) * 128))[c4];
      *(float4*)&Bsh[k][c4 * 4] = v;
    }
    __syncthreads();
#pragma unroll 4
    for (int k = 0; k < 64; ++k) {
      float aa[4] = {Ash[r0 + 0][k], Ash[r0 + 1][k], Ash[r0 + 2][k], Ash[r0 + 3][k]};
      float4 b0 = *(const float4*)&Bsh[k][c0];
      float4 b1 = *(const float4*)&Bsh[k][c0 + 64];
      float bb[8] = {b0.x, b0.y, b0.z, b0.w, b1.x, b1.y, b1.z, b1.w};
#pragma unroll
      for (int r = 0; r < 4; ++r)
#pragma unroll
        for (int j = 0; j < 8; ++j) acc[r][j] = fmaf(aa[r], bb[j], acc[r][j]);
    }
    __syncthreads();
  }

  float bv[8];
#pragma unroll
  for (int j = 0; j < 8; ++j)
    bv[j] = bias ? bias[j < 4 ? c0 + j : c0 + 60 + j] : 0.f;
#pragma unroll
  for (int r = 0; r < 4; ++r) {
    int gr = row0 + r0 + r;
    if (gr < nrows) {
      ushort4 lo, hi;
      lo.x = __half_as_ushort(__float2half((acc[r][0] + bv[0]) * LOG2E));
      lo.y = __half_as_ushort(__float2half((acc[r][1] + bv[1]) * LOG2E));
      lo.z = __half_as_ushort(__float2half((acc[r][2] + bv[2]) * LOG2E));
      lo.w = __half_as_ushort(__float2half((acc[r][3] + bv[3]) * LOG2E));
      hi.x = __half_as_ushort(__float2half((acc[r][4] + bv[4]) * LOG2E));
      hi.y = __half_as_ushort(__float2half((acc[r][5] + bv[5]) * LOG2E));
      hi.z = __half_as_ushort(__float2half((acc[r][6] + bv[6]) * LOG2E));
      hi.w = __half_as_ushort(__float2half((acc[r][7] + bv[7]) * LOG2E));
      // channel group tx -> halfs [tx*8 .. tx*8+8); group tx+16 for +64 channels
      *(ushort4*)(dstbase + (size_t)gr * 256 + tx * 8 + soff) = lo;
      *(ushort4*)(dstbase + (size_t)gr * 256 + (tx + 16) * 8 + soff) = hi;
    }
  }
}

// ------- e = softplus(edge_attr @ Wsh + bsh), 16 lanes/edge; fused dst histo ---
__global__ __launch_bounds__(256) void edge_e_kernel(const float* __restrict__ edge_attr,
                                                     const float* __restrict__ Wsh,
                                                     const float* __restrict__ bsh,
                                                     const int* __restrict__ eidx,
                                                     int* __restrict__ deg,
                                                     float* __restrict__ ebuf) {
  __shared__ float wsh[128];
  int tid = threadIdx.x;
  if (tid < 128) wsh[tid] = Wsh[tid];
  __syncthreads();
  // fused histogram: 16 edges per block
  if (tid < 16) {
    int e = blockIdx.x * 16 + tid;
    atomicAdd(&deg[eidx[EE + e]], 1);
  }
  int wave = tid >> 6, lane = tid & 63;
  int sub = lane >> 4, l16 = lane & 15;
  int edge = (blockIdx.x * 4 + wave) * 4 + sub;
  const float4* row = (const float4*)(edge_attr + (size_t)edge * 128);
  float4 v0 = row[l16], v1 = row[l16 + 16];
  float4 w0 = *(const float4*)&wsh[l16 * 4];
  float4 w1 = *(const float4*)&wsh[64 + l16 * 4];
  float p = v0.x * w0.x + v0.y * w0.y + v0.z * w0.z + v0.w * w0.w +
            v1.x * w1.x + v1.y * w1.y + v1.z * w1.z + v1.w * w1.w;
  p += __shfl_xor(p, 1);
  p += __shfl_xor(p, 2);
  p += __shfl_xor(p, 4);
  p += __shfl_xor(p, 8);
  if (l16 == 0) ebuf[edge] = softplus_fast(p + bsh[0]);
}

// ---------------- CSR build: single-block exclusive scan (int4, 4/thread) ------
__global__ __launch_bounds__(1024) void scan_kernel(const int* __restrict__ deg,
                                                    int* __restrict__ rowptr,
                                                    int* __restrict__ cur) {
  __shared__ int wscan[16];
  __shared__ int chunk_total_sh;
  int tid = threadIdx.x;
  int wid = tid >> 6, lane = tid & 63;
  int running = 0;
  for (int base = 0; base < NN; base += 4096) {
    int i0 = base + tid * 4;
    int4 v = make_int4(0, 0, 0, 0);
    if (i0 + 3 < NN) {
      v = *(const int4*)(deg + i0);
    } else {
      if (i0 < NN)     v.x = deg[i0];
      if (i0 + 1 < NN) v.y = deg[i0 + 1];
      if (i0 + 2 < NN) v.z = deg[i0 + 2];
      if (i0 + 3 < NN) v.w = deg[i0 + 3];
    }
    int t0 = v.x, t1 = t0 + v.y, t2 = t1 + v.z, t3 = t2 + v.w;
    int s = t3;
#pragma unroll
    for (int off = 1; off < 64; off <<= 1) {
      int t = __shfl_up(s, off);
      if (lane >= off) s += t;
    }
    if (lane == 63) wscan[wid] = s;
    __syncthreads();
    if (wid == 0 && lane < 16) {
      int w = wscan[lane];
#pragma unroll
      for (int off = 1; off < 16; off <<= 1) {
        int t = __shfl_up(w, off);
        if (lane >= off) w += t;
      }
      wscan[lane] = w;
      if (lane == 15) chunk_total_sh = w;
    }
    __syncthreads();
    int wexcl = (wid == 0) ? 0 : wscan[wid - 1];
    int texcl = running + wexcl + (s - t3);
    int4 r = make_int4(texcl, texcl + t0, texcl + t1, texcl + t2);
    if (i0 + 3 < NN) {
      *(int4*)(rowptr + i0) = r;
      *(int4*)(cur + i0) = r;
    } else {
      if (i0 < NN)     { rowptr[i0] = r.x;     cur[i0] = r.x; }
      if (i0 + 1 < NN) { rowptr[i0 + 1] = r.y; cur[i0 + 1] = r.y; }
      if (i0 + 2 < NN) { rowptr[i0 + 2] = r.z; cur[i0 + 2] = r.z; }
      if (i0 + 3 < NN) { rowptr[i0 + 3] = r.w; cur[i0 + 3] = r.w; }
    }
    running += chunk_total_sh;
    __syncthreads();
  }
  if (tid == 0) rowptr[NN] = EE;
}

// -------- CSR build: scatter packed (src, e-bits) into dst-sorted order --------
__global__ __launch_bounds__(256) void scatter_kernel(const int* __restrict__ eidx,
                                                      const float* __restrict__ ebuf,
                                                      int* __restrict__ cur,
                                                      int2* __restrict__ edges) {
  int e = blockIdx.x * 256 + threadIdx.x;
  if (e < EE) {
    int dst = eidx[EE + e];
    int pos = atomicAdd(&cur[dst], 1);
    edges[pos] = make_int2(eidx[e], __float_as_int(ebuf[e]));
  }
}

// ---------------- gather-side aggregation: 32 lanes per node, no atomics -------
// fp16 interleaved slabs: one 16B uint4 per lane delivers BOTH fj and sj
// fragments (8 halfs). Per edge: 1 packed int2 index load + 1 row gather.
// 2-deep clamped-index software pipeline hides L2/L3 gather latency.
__global__ __launch_bounds__(256) void aggregate_kernel(const int* __restrict__ rowptr,
                                                        const int2* __restrict__ edges,
                                                        const ushort* __restrict__ POwn,
                                                        const ushort* __restrict__ PGat,
                                                        float* __restrict__ aggr,
                                                        const float* __restrict__ Wf_e,
                                                        const float* __restrict__ Ws_e) {
  __shared__ float wfe[128], wse[128];
  int tid = threadIdx.x;
  if (tid < 128) wfe[tid] = Wf_e[tid] * LOG2E;
  else wse[tid - 128] = Ws_e[tid - 128] * LOG2E;
  __syncthreads();
  int slot = tid >> 5, lane = tid & 31;
  int node = blockIdx.x * 8 + slot;   // grid: 6250*8 == 50000
  const uint4* ownrow = (const uint4*)(POwn + (size_t)node * 256);
  uint4 o = ownrow[lane];
  float2 fi01 = __half22float2(*(const __half2*)&o.x);
  float2 fi23 = __half22float2(*(const __half2*)&o.y);
  float2 si01 = __half22float2(*(const __half2*)&o.z);
  float2 si23 = __half22float2(*(const __half2*)&o.w);
  float4 wf4 = *(const float4*)&wfe[lane * 4];
  float4 ws4 = *(const float4*)&wse[lane * 4];
  float4 acc = make_float4(0.f, 0.f, 0.f, 0.f);

  int beg = rowptr[node], end = rowptr[node + 1];
  if (beg < end) {
    const uint4* gat = (const uint4*)PGat;  // 32 uint4 per node row
    int2 eA = edges[beg];
    int2 eB = edges[min(beg + 1, end - 1)];
    uint4 gA = gat[(size_t)eA.x * 32 + lane];
    uint4 gB = gat[(size_t)eB.x * 32 + lane];
    for (int k = beg; k < end; ++k) {
      int2 eC = edges[min(k + 2, end - 1)];
      uint4 gC = gat[(size_t)eC.x * 32 + lane];
      float eV = __int_as_float(eA.y);
      float2 fj01 = __half22float2(*(const __half2*)&gA.x);
      float2 fj23 = __half22float2(*(const __half2*)&gA.y);
      float2 sj01 = __half22float2(*(const __half2*)&gA.z);
      float2 sj23 = __half22float2(*(const __half2*)&gA.w);
      float a2, b2, g, sp;
      a2 = fmaf(eV, wf4.x, fi01.x) + fj01.x;
      g  = fast_rcp(1.f + fast_exp2(-a2));
      b2 = fmaf(eV, ws4.x, si01.x) + sj01.x;
      sp = fmaxf(b2, 0.f) + fast_log2(1.f + fast_exp2(-fabsf(b2)));
      acc.x = fmaf(g, sp, acc.x);
      a2 = fmaf(eV, wf4.y, fi01.y) + fj01.y;
      g  = fast_rcp(1.f + fast_exp2(-a2));
      b2 = fmaf(eV, ws4.y, si01.y) + sj01.y;
      sp = fmaxf(b2, 0.f) + fast_log2(1.f + fast_exp2(-fabsf(b2)));
      acc.y = fmaf(g, sp, acc.y);
      a2 = fmaf(eV, wf4.z, fi23.x) + fj23.x;
      g  = fast_rcp(1.f + fast_exp2(-a2));
      b2 = fmaf(eV, ws4.z, si23.x) + sj23.x;
      sp = fmaxf(b2, 0.f) + fast_log2(1.f + fast_exp2(-fabsf(b2)));
      acc.z = fmaf(g, sp, acc.z);
      a2 = fmaf(eV, wf4.w, fi23.y) + fj23.y;
      g  = fast_rcp(1.f + fast_exp2(-a2));
      b2 = fmaf(eV, ws4.w, si23.y) + sj23.y;
      sp = fmaxf(b2, 0.f) + fast_log2(1.f + fast_exp2(-fabsf(b2)));
      acc.w = fmaf(g, sp, acc.w);
      eA = eB; gA = gB;
      eB = eC; gB = gC;
    }
  }
  acc.x *= LN2F; acc.y *= LN2F; acc.z *= LN2F; acc.w *= LN2F;
  ((float4*)(aggr + (size_t)node * 128))[lane] = acc;
}

// ---------------- per-channel sum / sumsq over aggr ----------------------------
__global__ __launch_bounds__(256) void stats_kernel(const float* __restrict__ aggr,
                                                    double* __restrict__ dstats) {
  int tid = threadIdx.x;
  int c = tid & 127, half = tid >> 7;
  int rbase = blockIdx.x * 512;
  float s = 0.f, q = 0.f;
  for (int i = 0; i < 256; ++i) {
    int r = rbase + half + i * 2;
    if (r < NN) {
      float v = aggr[(size_t)r * 128 + c];
      s += v;
      q += v * v;
    }
  }
  __shared__ float shs[256], shq[256];
  shs[tid] = s;
  shq[tid] = q;
  __syncthreads();
  if (tid < 128) {
    double ts = (double)shs[tid] + (double)shs[tid + 128];
    double tq = (double)shq[tid] + (double)shq[tid + 128];
    atomicAdd(&dstats[c], ts);
    atomicAdd(&dstats[128 + c], tq);
  }
}

// ---------------- fold BN into per-channel scale/shift -------------------------
__global__ void bn_params_kernel(const double* __restrict__ dstats,
                                 const float* __restrict__ gamma,
                                 const float* __restrict__ beta,
                                 float* __restrict__ scsh) {
  int c = threadIdx.x;
  double mean = dstats[c] / (double)NN;
  double var = dstats[128 + c] / (double)NN - mean * mean;
  double rs = 1.0 / sqrt(var + 1e-5);
  double sc = (double)gamma[c] * rs;
  scsh[c] = (float)sc;
  scsh[128 + c] = (float)((double)beta[c] - mean * sc);
}

// ---------------- y = 2*out + aggr*scale + shift (in-place on d_out) -----------
__global__ __launch_bounds__(256) void finalize_kernel(const float* __restrict__ outbuf,
                                                       const float* __restrict__ scsh,
                                                       float* __restrict__ dout) {
  __shared__ float sc[128], sh[128];
  int tid = threadIdx.x;
  if (tid < 128) sc[tid] = scsh[tid];
  else sh[tid - 128] = scsh[tid];
  __syncthreads();
  size_t i = (size_t)blockIdx.x * 256 + tid;
  size_t stride = (size_t)gridDim.x * 256;
  const float4* o4 = (const float4*)outbuf;
  float4* d4 = (float4*)dout;
  const size_t n4 = (size_t)NN * 32;
  for (; i < n4; i += stride) {
    int c4 = (int)(i & 31) * 4;
    float4 a = d4[i], o = o4[i];
    float4 r;
    r.x = 2.f * o.x + a.x * sc[c4 + 0] + sh[c4 + 0];
    r.y = 2.f * o.y + a.y * sc[c4 + 1] + sh[c4 + 1];
    r.z = 2.f * o.z + a.z * sc[c4 + 2] + sh[c4 + 2];
    r.w = 2.f * o.w + a.w * sc[c4 + 3] + sh[c4 + 3];
    d4[i] = r;
  }
}

extern "C" void kernel_launch(void* const* d_in, const int* in_sizes, int n_in,
                              void* d_out, int out_size, void* d_ws, size_t ws_size,
                              hipStream_t stream) {
  const float* h         = (const float*)d_in[0];
  const int*   eidx      = (const int*)d_in[1];
  const float* edge_attr = (const float*)d_in[3];
  const float* W0    = (const float*)d_in[4];
  const float* b0    = (const float*)d_in[5];
  const float* Wsh   = (const float*)d_in[6];
  const float* bsh   = (const float*)d_in[7];
  const float* Wf    = (const float*)d_in[8];
  const float* bf    = (const float*)d_in[9];
  const float* Ws    = (const float*)d_in[10];
  const float* bs    = (const float*)d_in[11];
  const float* gamma = (const float*)d_in[12];
  const float* beta  = (const float*)d_in[13];
  float* dout = (float*)d_out;

  // Workspace layout (~85 MB). All slab offsets 16B-aligned; edges 8B-aligned.
  char* ws = (char*)d_ws;
  const size_t NCb = (size_t)NN * 128 * 4;   // 25.6 MB (fp32 [NN,128])
  const size_t NHb = (size_t)NN * 256 * 2;   // 25.6 MB (fp16 [NN,256] interleaved)
  float*  outbuf = (float*)ws;                          // [NN,128] f32
  ushort* POwn   = (ushort*)(ws + NCb);                 // fp16 {fi4,si4} x32 groups
  ushort* PGat   = (ushort*)(ws + NCb + NHb);           // fp16 {fj4,sj4} x32 groups
  char*   p0     = ws + NCb + NHb * 2;
  float*  ebuf   = (float*)p0;                  p0 += (size_t)EE * 4;
  int2*   edges  = (int2*)p0;                   p0 += (size_t)EE * 8;
  double* dstats = (double*)p0;                 p0 += 256 * 8;
  float*  scsh   = (float*)p0;                  p0 += 256 * 4;
  int*    deg    = (int*)p0;                    p0 += (size_t)NN * 4;
  int*    rowptr = (int*)p0;                    p0 += (size_t)(NN + 4) * 4;  // padded
  int*    cur    = (int*)p0;

  // 1. zero deg + stats
  zero_kernel<<<(NN + 255) / 256, 256, 0, stream>>>(deg, (float*)dstats);

  // 2. out = softplus(h @ W0 + b0)
  const int gblocks = (NN + 63) / 64;
  gemm128_act<<<gblocks, 256, 0, stream>>>(h, W0, b0, outbuf, NN);

  // 3. all four P slabs in one dispatch, written fp16-interleaved (x LOG2E)
  gemm128_p4<<<dim3(gblocks, 4), 256, 0, stream>>>(outbuf, Wf, Ws, bf, bs,
                                                   POwn, PGat, NN);

  // 4. e = softplus(edge_attr @ Wsh + bsh)  + fused dst histogram
  edge_e_kernel<<<EE / 16, 256, 0, stream>>>(edge_attr, Wsh, bsh, eidx, deg, ebuf);

  // 5. CSR build by dst
  scan_kernel<<<1, 1024, 0, stream>>>(deg, rowptr, cur);
  scatter_kernel<<<(EE + 255) / 256, 256, 0, stream>>>(eidx, ebuf, cur, edges);

  // 6. gather-side aggregation (no atomics; writes aggr into d_out)
  aggregate_kernel<<<NN / 8, 256, 0, stream>>>(rowptr, edges, POwn, PGat, dout,
                                               Wf + 256 * 128, Ws + 256 * 128);

  // 7-9. batch stats, BN fold, finalize
  stats_kernel<<<(NN + 511) / 512, 256, 0, stream>>>(dout, dstats);
  bn_params_kernel<<<1, 128, 0, stream>>>(dstats, gamma, beta, scsh);
  finalize_kernel<<<2048, 256, 0, stream>>>(outbuf, scsh, dout);
}